// Round 3
// baseline (298.869 us; speedup 1.0000x reference)
//
#include <hip/hip_runtime.h>

#define BATCH   4096
#define IN_DIM  2048
#define OUT_DIM 14951
#define ROWS    4
#define NT1     512            // K1: 8 waves; 128 threads (2 waves) per row
#define NT2     256            // K2: fill-like streaming blocks
#define STRIDE  2052           // fused fallback only
#define EPS     1e-12f

typedef float nfloat4 __attribute__((ext_vector_type(4)));

// ===================== K1: FWHT2048 + L2-norm -> workspace =====================
// wy[b][i] = FWHT2048(x_b)[i], wscale[b] = -scale/||x_b||
__global__ __launch_bounds__(NT1, 4) void HC_fwht_kernel(
    const float* __restrict__ x,
    const float* __restrict__ scale,
    float* __restrict__ wy,
    float* __restrict__ wscale)
{
    __shared__ float y[ROWS * IN_DIM];   // 32 KB exchange buffer
    __shared__ float rss[ROWS * 2];

    const int tid = threadIdx.x;
    const int r   = tid >> 7;            // row within block (0..3)
    const int t   = tid & 127;           // thread within row (2 waves)
    const int b0  = blockIdx.x * ROWS;

    const float4* xv = reinterpret_cast<const float4*>(x + (size_t)(b0 + r) * IN_DIM) + 4 * t;
    float4 v0 = xv[0], v1 = xv[1], v2 = xv[2], v3 = xv[3];
    float a[16] = { v0.x, v0.y, v0.z, v0.w, v1.x, v1.y, v1.z, v1.w,
                    v2.x, v2.y, v2.z, v2.w, v3.x, v3.y, v3.z, v3.w };

    // sum of squares
    float ss = 0.f;
    #pragma unroll
    for (int k = 0; k < 16; ++k) ss += a[k] * a[k];
    #pragma unroll
    for (int off = 32; off > 0; off >>= 1) ss += __shfl_down(ss, off, 64);
    if ((tid & 63) == 0) rss[tid >> 6] = ss;

    // FWHT h=1..8 in registers
    #pragma unroll
    for (int h = 1; h < 16; h <<= 1) {
        #pragma unroll
        for (int g = 0; g < 16; g += 2 * h) {
            #pragma unroll
            for (int k = 0; k < h; ++k) {
                float u = a[g + k], w = a[g + k + h];
                a[g + k]     = u + w;
                a[g + k + h] = u - w;
            }
        }
    }

    // FWHT h=16..512 via shfl_xor (partner in same 64-lane wave)
    #pragma unroll
    for (int s = 0; s < 6; ++s) {
        const float sgn = (t & (1 << s)) ? -1.0f : 1.0f;
        #pragma unroll
        for (int k = 0; k < 16; ++k) {
            float recv = __shfl_xor(a[k], 1 << s, 64);
            a[k] = fmaf(sgn, a[k], recv);
        }
    }

    // h=1024: cross-wave via LDS; combine chunked (no p[16] pressure)
    float* yr = y + r * IN_DIM;
    #pragma unroll
    for (int k = 0; k < 4; ++k)
        *reinterpret_cast<float4*>(&yr[16 * t + 4 * k]) =
            make_float4(a[4 * k], a[4 * k + 1], a[4 * k + 2], a[4 * k + 3]);
    __syncthreads();

    if (tid < ROWS)
        wscale[b0 + tid] = -scale[0] * rsqrtf(fmaxf(rss[2 * tid] + rss[2 * tid + 1], EPS));

    const int   tp = t ^ 64;
    const float sg = (t < 64) ? 1.0f : -1.0f;   // lo: own+partner, hi: partner-own
    float4* wrow = reinterpret_cast<float4*>(wy + (size_t)(b0 + r) * IN_DIM);
    #pragma unroll
    for (int k = 0; k < 4; ++k) {
        float4 w = *reinterpret_cast<const float4*>(&yr[16 * tp + 4 * k]);
        float4 o;
        o.x = fmaf(sg, a[4 * k],     w.x);
        o.y = fmaf(sg, a[4 * k + 1], w.y);
        o.z = fmaf(sg, a[4 * k + 2], w.z);
        o.w = fmaf(sg, a[4 * k + 3], w.w);
        wrow[4 * t + k] = o;                   // plain store: K2 re-reads via L3
    }
}

// ===================== K2: out[b][j] = wscale[b]*wy[b][j&2047] + bias[j] =====================
// Alignment class C = b & 3: taking j = C + 4k makes the store address
// b*OUT_DIM + j == 0 (mod 4) -> aligned nontemporal dwordx4; window/bias reads
// stay on aligned vec4 pairs with compile-time component selects.
template<int C>
__device__ __forceinline__ void hc_out_body(const float* __restrict__ yl,
                                            const float* __restrict__ bias,
                                            float* __restrict__ orow, float sv)
{
    for (int k = threadIdx.x; k < 3736; k += NT2) {
        const int m4 = (4 * k) & (IN_DIM - 1);          // 4-aligned
        const float4 w0  = *reinterpret_cast<const float4*>(&yl[m4]);
        const float4 w1  = *reinterpret_cast<const float4*>(&yl[m4 + 4]);
        const float4 blo = *reinterpret_cast<const float4*>(&bias[4 * k]);
        const float4 bhi = *reinterpret_cast<const float4*>(&bias[4 * k + 4]);  // k<=3735: in-bounds
        const float wv[8] = { w0.x, w0.y, w0.z, w0.w, w1.x, w1.y, w1.z, w1.w };
        const float bv[8] = { blo.x, blo.y, blo.z, blo.w, bhi.x, bhi.y, bhi.z, bhi.w };
        nfloat4 o;
        o.x = fmaf(sv, wv[C + 0], bv[C + 0]);           // compile-time indices
        o.y = fmaf(sv, wv[C + 1], bv[C + 1]);
        o.z = fmaf(sv, wv[C + 2], bv[C + 2]);
        o.w = fmaf(sv, wv[C + 3], bv[C + 3]);
        __builtin_nontemporal_store(o, reinterpret_cast<nfloat4*>(&orow[C + 4 * k]));
    }
}

__global__ __launch_bounds__(NT2, 8) void HC_out_kernel(
    const float* __restrict__ wy,
    const float* __restrict__ wscale,
    const float* __restrict__ bias,
    float* __restrict__ out)
{
    __shared__ float yl[IN_DIM + 8];     // +pad for wrap window
    const int b   = blockIdx.x;
    const int tid = threadIdx.x;

    const float4* src  = reinterpret_cast<const float4*>(wy + (size_t)b * IN_DIM);
    float4*       dst4 = reinterpret_cast<float4*>(yl);
    float4 t0 = src[tid], t1 = src[tid + NT2];
    dst4[tid] = t0;
    dst4[tid + NT2] = t1;
    if (tid == 0) dst4[512] = t0;        // yl[2048..2051] = yl[0..3]
    const float sv = wscale[b];
    __syncthreads();

    float* orow = out + (size_t)b * OUT_DIM;
    switch (b & 3) {
        case 0: hc_out_body<0>(yl, bias, orow, sv); break;
        case 1: hc_out_body<1>(yl, bias, orow, sv); break;
        case 2: hc_out_body<2>(yl, bias, orow, sv); break;
        default: hc_out_body<3>(yl, bias, orow, sv); break;
    }

    // leftovers: exactly 7 scalars per row: heads [0,C) + tail [C+14944, 14951)
    const int C = b & 3;
    if (tid < 7) {
        const int j = (tid < C) ? tid : (C + 14944 + (tid - C));
        orow[j] = fmaf(sv, yl[j & (IN_DIM - 1)], bias[j]);
    }
}

// ===================== fused fallback (verified R2 kernel) =====================
__global__ __launch_bounds__(NT1, 8) void HadamardClassifier_44487271252814_kernel(
    const float* __restrict__ x,
    const float* __restrict__ scale,
    const float* __restrict__ bias,
    float* __restrict__ out)
{
    __shared__ float y[ROWS * STRIDE];
    __shared__ float rss[ROWS * 2];
    __shared__ float srow[ROWS];

    const int tid = threadIdx.x;
    const int r   = tid >> 7;
    const int t   = tid & 127;
    const int b0  = blockIdx.x * ROWS;

    const float4* xv = reinterpret_cast<const float4*>(x + (size_t)(b0 + r) * IN_DIM) + 4 * t;
    float4 v0 = xv[0], v1 = xv[1], v2 = xv[2], v3 = xv[3];
    float a[16] = { v0.x, v0.y, v0.z, v0.w, v1.x, v1.y, v1.z, v1.w,
                    v2.x, v2.y, v2.z, v2.w, v3.x, v3.y, v3.z, v3.w };

    float ss = 0.f;
    #pragma unroll
    for (int k = 0; k < 16; ++k) ss += a[k] * a[k];
    #pragma unroll
    for (int off = 32; off > 0; off >>= 1) ss += __shfl_down(ss, off, 64);
    if ((tid & 63) == 0) rss[tid >> 6] = ss;

    #pragma unroll
    for (int h = 1; h < 16; h <<= 1) {
        #pragma unroll
        for (int g = 0; g < 16; g += 2 * h) {
            #pragma unroll
            for (int k = 0; k < h; ++k) {
                float u = a[g + k], w = a[g + k + h];
                a[g + k]     = u + w;
                a[g + k + h] = u - w;
            }
        }
    }
    #pragma unroll
    for (int s = 0; s < 6; ++s) {
        const float sgn = (t & (1 << s)) ? -1.0f : 1.0f;
        #pragma unroll
        for (int k = 0; k < 16; ++k) {
            float recv = __shfl_xor(a[k], 1 << s, 64);
            a[k] = fmaf(sgn, a[k], recv);
        }
    }

    float* yr = y + r * STRIDE;
    #pragma unroll
    for (int k = 0; k < 4; ++k)
        *reinterpret_cast<float4*>(&yr[16 * t + 4 * k]) =
            make_float4(a[4 * k], a[4 * k + 1], a[4 * k + 2], a[4 * k + 3]);
    __syncthreads();

    if (tid < ROWS)
        srow[tid] = -scale[0] * rsqrtf(fmaxf(rss[2 * tid] + rss[2 * tid + 1], EPS));

    const int tp = t ^ 64;
    float p[16];
    #pragma unroll
    for (int k = 0; k < 4; ++k) {
        float4 w = *reinterpret_cast<const float4*>(&yr[16 * tp + 4 * k]);
        p[4 * k] = w.x; p[4 * k + 1] = w.y; p[4 * k + 2] = w.z; p[4 * k + 3] = w.w;
    }
    __syncthreads();

    const float sg = (t < 64) ? 1.0f : -1.0f;
    #pragma unroll
    for (int k = 0; k < 16; ++k) a[k] = fmaf(sg, a[k], p[k]);

    #pragma unroll
    for (int k = 0; k < 4; ++k)
        *reinterpret_cast<float4*>(&yr[16 * t + 4 * k]) =
            make_float4(a[4 * k], a[4 * k + 1], a[4 * k + 2], a[4 * k + 3]);
    if (t == 0)
        *reinterpret_cast<float4*>(&yr[2048]) = make_float4(a[0], a[1], a[2], a[3]);
    __syncthreads();

    const float sv0 = srow[0], sv1 = srow[1], sv2 = srow[2], sv3 = srow[3];
    const float* y0p = y;
    const float* y1p = y + STRIDE;
    const float* y2p = y + 2 * STRIDE;
    const float* y3p = y + 3 * STRIDE;

    for (int k = tid; k < (OUT_DIM >> 2) - 1; k += NT1) {
        const int e  = 4 * k;
        const int m4 = e & (IN_DIM - 1);
        const float4 blo = *reinterpret_cast<const float4*>(&bias[e]);
        const float4 bhi = *reinterpret_cast<const float4*>(&bias[e + 4]);
        const size_t ob = (size_t)b0 * OUT_DIM + e;
        {
            const float4 w0 = *reinterpret_cast<const float4*>(&y0p[m4]);
            nfloat4 o;
            o.x = fmaf(sv0, w0.x, blo.x);
            o.y = fmaf(sv0, w0.y, blo.y);
            o.z = fmaf(sv0, w0.z, blo.z);
            o.w = fmaf(sv0, w0.w, blo.w);
            __builtin_nontemporal_store(o, reinterpret_cast<nfloat4*>(&out[ob]));
        }
        {
            const float4 w0 = *reinterpret_cast<const float4*>(&y1p[m4]);
            const float4 w1 = *reinterpret_cast<const float4*>(&y1p[m4 + 4]);
            nfloat4 o;
            o.x = fmaf(sv1, w0.y, blo.y);
            o.y = fmaf(sv1, w0.z, blo.z);
            o.z = fmaf(sv1, w0.w, blo.w);
            o.w = fmaf(sv1, w1.x, bhi.x);
            __builtin_nontemporal_store(o, reinterpret_cast<nfloat4*>(&out[ob + OUT_DIM + 1]));
        }
        {
            const float4 w0 = *reinterpret_cast<const float4*>(&y2p[m4]);
            const float4 w1 = *reinterpret_cast<const float4*>(&y2p[m4 + 4]);
            nfloat4 o;
            o.x = fmaf(sv2, w0.z, blo.z);
            o.y = fmaf(sv2, w0.w, blo.w);
            o.z = fmaf(sv2, w1.x, bhi.x);
            o.w = fmaf(sv2, w1.y, bhi.y);
            __builtin_nontemporal_store(o, reinterpret_cast<nfloat4*>(&out[ob + 2 * OUT_DIM + 2]));
        }
        {
            const float4 w0 = *reinterpret_cast<const float4*>(&y3p[m4]);
            const float4 w1 = *reinterpret_cast<const float4*>(&y3p[m4 + 4]);
            nfloat4 o;
            o.x = fmaf(sv3, w0.w, blo.w);
            o.y = fmaf(sv3, w1.x, bhi.x);
            o.z = fmaf(sv3, w1.y, bhi.y);
            o.w = fmaf(sv3, w1.z, bhi.z);
            __builtin_nontemporal_store(o, reinterpret_cast<nfloat4*>(&out[ob + 3 * OUT_DIM + 3]));
        }
    }

    if (tid < 28) {
        const int rr  = tid / 7;
        const int idx = tid - rr * 7;
        const int j   = (idx < rr) ? idx : (14944 + idx);
        out[(size_t)(b0 + rr) * OUT_DIM + j] =
            fmaf(srow[rr], y[rr * STRIDE + (j & (IN_DIM - 1))], bias[j]);
    }
}

extern "C" void kernel_launch(void* const* d_in, const int* in_sizes, int n_in,
                              void* d_out, int out_size, void* d_ws, size_t ws_size,
                              hipStream_t stream) {
    const float* x     = (const float*)d_in[0];
    const float* scale = (const float*)d_in[1];
    const float* bias  = (const float*)d_in[2];
    float* out = (float*)d_out;

    const size_t ws_needed = (size_t)BATCH * IN_DIM * sizeof(float) + BATCH * sizeof(float);
    if (d_ws && ws_size >= ws_needed) {
        float* wy     = (float*)d_ws;
        float* wscale = (float*)d_ws + (size_t)BATCH * IN_DIM;
        hipLaunchKernelGGL(HC_fwht_kernel, dim3(BATCH / ROWS), dim3(NT1), 0, stream,
                           x, scale, wy, wscale);
        hipLaunchKernelGGL(HC_out_kernel, dim3(BATCH), dim3(NT2), 0, stream,
                           wy, wscale, bias, out);
    } else {
        hipLaunchKernelGGL(HadamardClassifier_44487271252814_kernel,
                           dim3(BATCH / ROWS), dim3(NT1), 0, stream,
                           x, scale, bias, out);
    }
}